// Round 5
// baseline (10.775 us; speedup 1.0000x reference)
//
#include <hip/hip_runtime.h>
#include <hip/hip_bf16.h>

__device__ __forceinline__ void ce(float& a, float& b) {
    float t = fminf(a, b); b = fmaxf(a, b); a = t;
}
__device__ __forceinline__ void s3(float& a, float& b, float& c) {
    ce(a, b); ce(a, c); ce(b, c);
}

__device__ __forceinline__ void merge21(float x0, float x1, float y0,
                                        float& p0, float& p1, float& p2) {
    ce(x0, y0);
    p0 = x0; p1 = y0; p2 = x1; ce(p1, p2);
}

// merge sorted triples -> w0..w5
__device__ __forceinline__ void merge33(float a0, float a1, float a2,
                                        float b0, float b1, float b2,
                                        float& w0, float& w1, float& w2,
                                        float& w3, float& w4, float& w5) {
    float x0 = a0, x1 = a2, y0 = b0, y1 = b2;
    ce(x0, y0); ce(x1, y1); ce(x1, y0);
    float e0 = a1, e1 = b1; ce(e0, e1);
    w0 = x0;
    w1 = x1; w2 = e0; ce(w1, w2);
    w3 = y0; w4 = e1; ce(w3, w4);
    w5 = y1;
}

// merge sorted-6 with sorted-3 -> full sorted 9
__device__ __forceinline__ void merge63(float c0, float c1, float c2, float c3, float c4, float c5,
                                        float d0, float d1, float d2,
                                        float& w0, float& w1, float& w2, float& w3, float& w4,
                                        float& w5, float& w6, float& w7, float& w8) {
    float p0, p1, p2; merge21(c0, c4, d0, p0, p1, p2);
    float q0 = c2, q1 = d2; ce(q0, q1);
    float o0 = p0, o1 = p1, o2 = q0; ce(o1, o2);
    float o3 = p2, o4 = q1; ce(o3, o4);
    float r0, r1, r2; merge21(c1, c5, d1, r0, r1, r2);
    float e0 = r0, e1 = r1, e2 = c3; ce(e1, e2);
    float e3 = r2;
    w0 = o0;
    w1 = o1; w2 = e0; ce(w1, w2);
    w3 = o2; w4 = e1; ce(w3, w4);
    w5 = o3; w6 = e2; ce(w5, w6);
    w7 = o4; w8 = e3; ce(w7, w8);
}

// MAD from sorted 9: devs form two sorted 4-runs around m=w4.
__device__ __forceinline__ float mad_sorted9(float w0, float w1, float w2, float w3, float w4,
                                             float w5, float w6, float w7, float w8) {
    float m = w4;
    float m0 = fminf(m - w3, w8 - m);
    float m1 = fminf(m - w2, w7 - m);
    float m2 = fminf(m - w1, w6 - m);
    float m3 = fminf(m - w0, w5 - m);
    return fmaxf(fmaxf(m0, m1), fmaxf(m2, m3));
}

__device__ __forceinline__ float mad_px(const float* pm, const float* d) {
    float w0, w1, w2, w3, w4, w5, w6, w7, w8;
    merge63(pm[0], pm[1], pm[2], pm[3], pm[4], pm[5], d[0], d[1], d[2],
            w0, w1, w2, w3, w4, w5, w6, w7, w8);
    return mad_sorted9(w0, w1, w2, w3, w4, w5, w6, w7, w8);
}

// One wave per PAIR of image rows: 64 lanes x 8 px x 2 rows.
// Loads 4 input rows (2 float4/lane each); halo via intra-wave shuffles.
__global__ void __launch_bounds__(256)
mad_kernel(const float* __restrict__ x, float* __restrict__ out) {
    const int W = 512;
    int lane = threadIdx.x & 63;
    int wid  = threadIdx.x >> 6;
    int rp   = blockIdx.x * 4 + wid;     // row-pair id: 0..2047
    int b    = rp >> 8;                  // batch
    int py0  = (rp & 255) << 1;          // first output row (even)

    const float* base = x + ((size_t)(b * 3 + 1)) * (512 * 512);

    // 4 input rows: py0-1, py0, py0+1, py0+2 (reflect at both edges)
    int yr0 = (py0 == 0)   ? 1   : py0 - 1;
    int yr3 = (py0 == 510) ? 510 : py0 + 2;

    int c = lane << 3;   // 8 pixels per lane
    float4 ra[4], rb[4];
    {
        const float* p0 = base + yr0 * W + c;
        const float* p1 = base + py0 * W + c;
        const float* p2 = base + (py0 + 1) * W + c;
        const float* p3 = base + yr3 * W + c;
        ra[0] = *reinterpret_cast<const float4*>(p0);
        rb[0] = *reinterpret_cast<const float4*>(p0 + 4);
        ra[1] = *reinterpret_cast<const float4*>(p1);
        rb[1] = *reinterpret_cast<const float4*>(p1 + 4);
        ra[2] = *reinterpret_cast<const float4*>(p2);
        rb[2] = *reinterpret_cast<const float4*>(p2 + 4);
        ra[3] = *reinterpret_cast<const float4*>(p3);
        rb[3] = *reinterpret_cast<const float4*>(p3 + 4);
    }

    // halo per loaded row: left = prev lane's rb.w; right = next lane's ra.x
    float L[4], R[4];
#pragma unroll
    for (int i = 0; i < 4; ++i) {
        L[i] = __shfl_up(rb[i].w, 1);
        R[i] = __shfl_down(ra[i].x, 1);
    }
    if (lane == 0) {
#pragma unroll
        for (int i = 0; i < 4; ++i) L[i] = ra[i].y;   // reflect col -1 -> 1
    }
    if (lane == 63) {
#pragma unroll
        for (int i = 0; i < 4; ++i) R[i] = rb[i].z;   // reflect col 512 -> 510
    }

#pragma unroll
    for (int k = 0; k < 2; ++k) {       // two output rows: use loaded rows k, k+1, k+2
        const int i0 = k, i1 = k + 1, i2 = k + 2;
        float col[10][3];
        col[0][0] = L[i0];    col[0][1] = L[i1];    col[0][2] = L[i2];
        col[1][0] = ra[i0].x; col[1][1] = ra[i1].x; col[1][2] = ra[i2].x;
        col[2][0] = ra[i0].y; col[2][1] = ra[i1].y; col[2][2] = ra[i2].y;
        col[3][0] = ra[i0].z; col[3][1] = ra[i1].z; col[3][2] = ra[i2].z;
        col[4][0] = ra[i0].w; col[4][1] = ra[i1].w; col[4][2] = ra[i2].w;
        col[5][0] = rb[i0].x; col[5][1] = rb[i1].x; col[5][2] = rb[i2].x;
        col[6][0] = rb[i0].y; col[6][1] = rb[i1].y; col[6][2] = rb[i2].y;
        col[7][0] = rb[i0].z; col[7][1] = rb[i1].z; col[7][2] = rb[i2].z;
        col[8][0] = rb[i0].w; col[8][1] = rb[i1].w; col[8][2] = rb[i2].w;
        col[9][0] = R[i0];    col[9][1] = R[i1];    col[9][2] = R[i2];
#pragma unroll
        for (int i = 0; i < 10; ++i) s3(col[i][0], col[i][1], col[i][2]);

        float pm[5][6];
#pragma unroll
        for (int i = 0; i < 5; ++i)
            merge33(col[2*i][0], col[2*i][1], col[2*i][2],
                    col[2*i+1][0], col[2*i+1][1], col[2*i+1][2],
                    pm[i][0], pm[i][1], pm[i][2], pm[i][3], pm[i][4], pm[i][5]);

        float o[8];
#pragma unroll
        for (int j = 0; j < 8; ++j) {
            const int pi = (j + 1) >> 1;
            const int ei = (j & 1) ? j : j + 2;
            o[j] = mad_px(pm[pi], col[ei]);
        }

        float* orow = out + ((size_t)(b * 512 + py0 + k)) * W + c;
        *reinterpret_cast<float4*>(orow)     = make_float4(o[0], o[1], o[2], o[3]);
        *reinterpret_cast<float4*>(orow + 4) = make_float4(o[4], o[5], o[6], o[7]);
    }
}

extern "C" void kernel_launch(void* const* d_in, const int* in_sizes, int n_in,
                              void* d_out, int out_size, void* d_ws, size_t ws_size,
                              hipStream_t stream) {
    const float* x = (const float*)d_in[0];
    float* out = (float*)d_out;
    const int rowpairs = 8 * 256;      // one wave per 2 rows
    const int block = 256;             // 4 waves per block
    const int grid = rowpairs / 4;     // 512 blocks
    mad_kernel<<<grid, block, 0, stream>>>(x, out);
}